// Round 9
// baseline (144.624 us; speedup 1.0000x reference)
//
#include <hip/hip_runtime.h>

#define N_NODES 50000
#define N_EDGES 800000
#define IN_DIM 128
#define OUT_DIM 64
#define CAP 64            // max row degree ~35 (Binomial(800k,1/50k), mean 16), 64 is safe
#define PARTS 8           // row partitions == XCD count
#define ROWS_PER_PART 6250
#define CHUNKS 1024
#define EDGES_PER_CHUNK 782    // 1024*782 = 800768 >= 800000 (guarded)

// Block layout: GEMM blocks FIRST so they are co-resident with the bucket
// blocks. 784%8==0 keeps the bucket blocks' blockIdx%8 == XCD mapping intact.
#define GEMM_BLOCKS 784                  // 784*4 waves = 3136 >= 3125 groups
#define BUCKET_BLOCKS (CHUNKS * PARTS)   // 8192
#define TOTAL_BLOCKS (GEMM_BLOCKS + BUCKET_BLOCKS)

// workspace layout (bytes), 16B-aligned
#define OFF_HID 0u          // bf16 hidden: 50000*64*2 = 6,400,000
#define OFF_DEG 6400000u    // int deg: 200,000
#define OFF_BKT 6600192u    // int2 bucket: 12500 groups * 4*CAP * 8B = 25,600,000

typedef short short8 __attribute__((ext_vector_type(8)));
typedef float f32x4 __attribute__((ext_vector_type(4)));

__device__ __forceinline__ unsigned short bf_rne(float f) {
    unsigned u = __float_as_uint(f);
    u += 0x7fffu + ((u >> 16) & 1u);   // round-to-nearest-even
    return (unsigned short)(u >> 16);
}
__device__ __forceinline__ float bf_lo(unsigned u) { return __uint_as_float(u << 16); }
__device__ __forceinline__ float bf_hi(unsigned u) { return __uint_as_float(u & 0xffff0000u); }

// Bucket layout, GROUP-INTERLEAVED by 4 rows (kept from R8: neutral on writes
// but gives agg perfectly coalesced 512-B stage reads):
//   slot `pos` of row `r` -> bucket[(r>>2)*(4*CAP) + pos*4 + (r&3)]
__device__ __forceinline__ size_t bslot(int r, int pos) {
    return (size_t)(r >> 2) * (4 * CAP) + pos * 4 + (r & 3);
}

// First bucket-group owned by XCD partition p (groups straddling a partition
// boundary are assigned to the lower partition; locality-only, correctness
// is global).  gstart(p) = ceil(p*6250/4).
__device__ __forceinline__ int gstart(int p) { return (p * ROWS_PER_PART + 3) >> 2; }

// ---------------------------------------------------------------------------
// FUSED kernel. blocks [0, 784): MFMA GEMM hidden = x @ w.
// blocks [784, 784+8192): edge bucketing, XCD-partitioned (part = bb&7 ==
// XCD; R5 proved removing this costs +20 us). CHUNKS=1024 -> 3 edges/thread,
// all loaded up-front, 3 independent atomic->store chains, 2x block-level
// TLP vs R8 (R6->R7's identical step gained 5 us).
// ---------------------------------------------------------------------------
__global__ __launch_bounds__(256) void fused_kernel(
        const float* __restrict__ x, const float* __restrict__ w,
        unsigned short* __restrict__ hidb,
        const int* __restrict__ erow, const int* __restrict__ ecol,
        const float* __restrict__ eval,
        int* __restrict__ deg, int2* __restrict__ bucket) {
    if (blockIdx.x >= GEMM_BLOCKS) {
        const int bb = blockIdx.x - GEMM_BLOCKS;
        const int part = bb & (PARTS - 1);           // == XCD id
        const int chunk = bb >> 3;
        const int rlo = part * ROWS_PER_PART;
        const int e0 = chunk * EDGES_PER_CHUNK;

        int r[3], c[3];
        float v[3];
        bool ok[3];
        #pragma unroll
        for (int t = 0; t < 3; ++t) {
            const int e = e0 + threadIdx.x + t * 256;   // max 767 < 782
            ok[t] = e < N_EDGES;
            r[t] = ok[t] ? erow[e] : -1;
            c[t] = ok[t] ? ecol[e] : 0;
            v[t] = ok[t] ? eval[e] : 0.f;
        }
        #pragma unroll
        for (int t = 0; t < 3; ++t) {
            if (ok[t] && (unsigned)(r[t] - rlo) < (unsigned)ROWS_PER_PART) {
                const int pos = atomicAdd(&deg[r[t]], 1);
                if (pos < CAP)
                    bucket[bslot(r[t], pos)] = make_int2(c[t], __float_as_int(v[t]));
            }
        }
        // tail: slots 768..781 (tid < 14)
        const int it = threadIdx.x + 768;
        const int e = e0 + it;
        if (it < EDGES_PER_CHUNK && e < N_EDGES) {
            const int rt = erow[e];
            const int ct = ecol[e];
            const float vt = eval[e];
            if ((unsigned)(rt - rlo) < (unsigned)ROWS_PER_PART) {
                const int pos = atomicAdd(&deg[rt], 1);
                if (pos < CAP) bucket[bslot(rt, pos)] = make_int2(ct, __float_as_int(vt));
            }
        }
        return;
    }

    // ---- GEMM path: hidden(bf16) = x @ w, one wave per 16-node group ----
    __shared__ __attribute__((aligned(16))) unsigned short smem[16 * 64 * 8];  // 16 KB

    const int tid = threadIdx.x;
    const int lane = tid & 63;
    const int wid = tid >> 6;

    // stage w into B-fragment order — coalesced float4 global reads,
    // scattered cheap LDS u16 writes.
    #pragma unroll
    for (int it = 0; it < 8; ++it) {
        const int e = it * 1024 + tid * 4;
        const f32x4 wv = *(const f32x4*)(w + e);
        const int k = e >> 6;
        const int n0 = e & 63;
        const int c = k >> 5, j = k & 7, lhi = ((k >> 3) & 3) * 16;
        #pragma unroll
        for (int m = 0; m < 4; ++m) {
            const int n = n0 + m;
            const int t = n >> 4;
            const int ln = lhi + (n & 15);
            smem[((c * 4 + t) * 64 + ln) * 8 + j] = bf_rne(wv[m]);
        }
    }
    __syncthreads();

    const int group = blockIdx.x * 4 + wid;   // 16-node group id

    short8 bf[16];
    if (group < N_NODES / 16) {
        #pragma unroll
        for (int f = 0; f < 16; ++f)
            bf[f] = *(const short8*)&smem[(f * 64 + lane) * 8];
    }
    __syncthreads();   // all waves have frags in regs -> smem reusable

    if (group < N_NODES / 16) {
        const int node0 = group * 16;
        f32x4 acc[4] = {{0, 0, 0, 0}, {0, 0, 0, 0}, {0, 0, 0, 0}, {0, 0, 0, 0}};

        #pragma unroll
        for (int c = 0; c < 4; ++c) {
            const float* xr = x + (size_t)(node0 + (lane & 15)) * IN_DIM + c * 32 + (lane >> 4) * 8;
            const f32x4 a0 = __builtin_nontemporal_load((const f32x4*)xr);   // read-once
            const f32x4 a1 = __builtin_nontemporal_load((const f32x4*)(xr + 4));
            short8 af;
            af[0] = (short)bf_rne(a0[0]); af[1] = (short)bf_rne(a0[1]);
            af[2] = (short)bf_rne(a0[2]); af[3] = (short)bf_rne(a0[3]);
            af[4] = (short)bf_rne(a1[0]); af[5] = (short)bf_rne(a1[1]);
            af[6] = (short)bf_rne(a1[2]); af[7] = (short)bf_rne(a1[3]);
            #pragma unroll
            for (int t = 0; t < 4; ++t)
                acc[t] = __builtin_amdgcn_mfma_f32_16x16x32_bf16(af, bf[c * 4 + t], acc[t], 0, 0, 0);
        }

        // epilogue: D[m][n] -> smem bounce -> global.  Row stride PADDED to
        // 72 shorts (was 64): rows land on distinct bank sets (2-way residue
        // only, which is free) — kills the 1.53M measured conflict cycles.
        // Slice per wave: 16*72 = 1152 shorts <= 2048 available.
        unsigned short* obuf = smem + wid * 2048;
        #pragma unroll
        for (int t = 0; t < 4; ++t)
            #pragma unroll
            for (int r = 0; r < 4; ++r)
                obuf[((lane >> 4) * 4 + r) * 72 + t * 16 + (lane & 15)] = bf_rne(acc[t][r]);
        // readback: lane covers elements [lane*16, lane*16+16) of the 16x64
        // tile = row m=lane>>2, cols (lane&3)*16.. ; base (lane>>2)*72+
        // (lane&3)*16 shorts is 16B-aligned since 72*2=144 and 16*2=32.
        const int rb = (lane >> 2) * 72 + (lane & 3) * 16;
        const uint4 o0 = *(const uint4*)&obuf[rb];
        const uint4 o1 = *(const uint4*)&obuf[rb + 8];
        char* dst = (char*)hidb + (size_t)node0 * (OUT_DIM * 2) + lane * 32;
        *(uint4*)dst = o0;
        *(uint4*)(dst + 16) = o1;
    }
}

// ---------------------------------------------------------------------------
// Aggregate, XCD-PINNED: block b runs on XCD b&7 (round-robin dispatch) and
// processes only bucket groups its XCD wrote during fused -> stage reads hit
// home-L2 lines if they survive the kernel boundary. 4 waves/block, one
// group (4 rows) per wave; 16 lanes x 8 B cover the 128-B hidden row.
// Gathers in 16-deep windows (window 1 unconditional, window 2 one guard).
// ---------------------------------------------------------------------------
__device__ __forceinline__ void proc16(const unsigned short* __restrict__ hidb,
                                       int2 P, int base,
                                       int q, int l, int d, float4& acc) {
    unsigned long long u[16];
    float vv[16];
    #pragma unroll
    for (int e = 0; e < 16; ++e) {
        const int src = (e << 2) | q;        // lane holding (row q, slot base+e)
        int c = __shfl(P.x, src);
        const int vi = __shfl(P.y, src);
        const bool act = (base + e) < d;
        c = act ? c : 0;
        vv[e] = act ? __int_as_float(vi) : 0.f;
        u[e] = *(const unsigned long long*)&hidb[(size_t)c * OUT_DIM + 4 * l];
    }
    #pragma unroll
    for (int e = 0; e < 16; ++e) {
        const float v = vv[e];
        const unsigned ulo = (unsigned)u[e];
        const unsigned uhi = (unsigned)(u[e] >> 32);
        acc.x = fmaf(v, bf_lo(ulo), acc.x);
        acc.y = fmaf(v, bf_hi(ulo), acc.y);
        acc.z = fmaf(v, bf_lo(uhi), acc.z);
        acc.w = fmaf(v, bf_hi(uhi), acc.w);
    }
}

#define AGG_BLOCKS_PER_XCD 391           // ceil(1564 groups / 4 waves)
#define AGG_BLOCKS (AGG_BLOCKS_PER_XCD * 8)   // 3128

__global__ __launch_bounds__(256) void agg_kernel(const unsigned short* __restrict__ hidb,
                                                  const int* __restrict__ deg,
                                                  const int2* __restrict__ bucket,
                                                  const float* __restrict__ b,
                                                  float* __restrict__ out) {
    const int tid = threadIdx.x;
    const int lane = tid & 63;
    const int wid = tid >> 6;
    const int q = lane >> 4;        // row within the wave's group
    const int l = lane & 15;        // dims 4l .. 4l+3

    const int xcd = blockIdx.x & 7;
    const int idx = blockIdx.x >> 3;
    const int g0 = gstart(xcd);
    const int gend = gstart(xcd + 1);
    const int g = g0 + idx * 4 + wid;            // bucket group (4 rows)
    const bool valid = g < gend;
    const int gc = valid ? g : (gend - 1);       // clamp (duplicate work is benign-free, writes guarded)
    const int row = gc * 4 + q;                  // row < 50000 always (gc <= 12499)

    const int d = valid ? min(deg[row], CAP) : 0;
    const int2* __restrict__ gp = bucket + (size_t)gc * (4 * CAP);

    // wave-uniform max degree over the 4 rows (uniform trip counts)
    int dmax = d;
    dmax = max(dmax, __shfl_xor(dmax, 16));
    dmax = max(dmax, __shfl_xor(dmax, 32));

    // stage first 32 slots x 4 rows: two contiguous 512-B reads
    const int2 pa = gp[lane];        // (row lane&3, slot lane>>2)
    const int2 pb = gp[64 + lane];   // (row lane&3, slot 16+(lane>>2))

    float4 acc = make_float4(0.f, 0.f, 0.f, 0.f);

    proc16(hidb, pa, 0, q, l, d, acc);                  // unconditional window
    if (dmax > 16) proc16(hidb, pb, 16, q, l, d, acc);  // one guarded window
    for (int base = 32; base < dmax; base += 16) {      // rare tail (P ~ 1e-4)
        const int2 pc = gp[base * 4 + lane];
        proc16(hidb, pc, base, q, l, d, acc);
    }

    if (valid) {
        const float4 bb = *(const float4*)&b[4 * l];
        float4 o;
        o.x = fmaxf(acc.x + bb.x, 0.f);
        o.y = fmaxf(acc.y + bb.y, 0.f);
        o.z = fmaxf(acc.z + bb.z, 0.f);
        o.w = fmaxf(acc.w + bb.w, 0.f);
        *(float4*)&out[(size_t)row * OUT_DIM + 4 * l] = o;
    }
}

extern "C" void kernel_launch(void* const* d_in, const int* in_sizes, int n_in,
                              void* d_out, int out_size, void* d_ws, size_t ws_size,
                              hipStream_t stream) {
    const float* x    = (const float*)d_in[0];
    const int*   erow = (const int*)d_in[1];
    const int*   ecol = (const int*)d_in[2];
    const float* eval = (const float*)d_in[3];
    const float* w    = (const float*)d_in[4];
    const float* b    = (const float*)d_in[5];
    float* out = (float*)d_out;

    char* ws = (char*)d_ws;
    unsigned short* hidb = (unsigned short*)(ws + OFF_HID);
    int*  deg    = (int*)(ws + OFF_DEG);
    int2* bucket = (int2*)(ws + OFF_BKT);

    hipMemsetAsync(deg, 0, N_NODES * sizeof(int), stream);

    // 1) fused: GEMM (blocks 0..783) overlapped with XCD-partitioned bucket
    fused_kernel<<<TOTAL_BLOCKS, 256, 0, stream>>>(
        x, w, hidb, erow, ecol, eval, deg, bucket);

    // 2) per-row gather-accumulate, XCD-pinned to the bucket writer
    agg_kernel<<<AGG_BLOCKS, 256, 0, stream>>>(hidb, deg, bucket, b, out);
}